// Round 6
// baseline (653.222 us; speedup 1.0000x reference)
//
#include <hip/hip_runtime.h>

#define IN_F 4096
#define OUT_F 16384
#define MTOK 8192   // B*S

#define BM 256
#define BN 256
#define BKB 128                 // K-bytes (=elements, i8) per K-tile
#define NKT (IN_F / BKB)        // 32 K-tiles
#define NIT (NKT / 2)           // 16 iterations, 2 K-tiles each

typedef __attribute__((ext_vector_type(4)))  int   i32x4;
typedef __attribute__((ext_vector_type(4)))  float f32x4;

__device__ __forceinline__ void gload_lds16(const void* g, void* l) {
    __builtin_amdgcn_global_load_lds(
        (const __attribute__((address_space(1))) void*)g,
        (__attribute__((address_space(3))) void*)l,
        16, 0, 0);
}

// ---------------------------------------------------------------------------
// Kernel 1: per-token absmax -> int8 quantize x, store scale
// ---------------------------------------------------------------------------
__global__ __launch_bounds__(256) void k_quant(const float* __restrict__ x,
                                               char* __restrict__ xq,
                                               float* __restrict__ xs) {
    const int m = blockIdx.x;
    const int t = threadIdx.x;
    const float* xrow = x + (size_t)m * IN_F;

    f32x4 v[4];
    float mx = 0.f;
#pragma unroll
    for (int i = 0; i < 4; ++i) {
        v[i] = *(const f32x4*)&xrow[(i * 256 + t) * 4];
        mx = fmaxf(mx, fmaxf(fmaxf(fabsf(v[i].x), fabsf(v[i].y)),
                             fmaxf(fabsf(v[i].z), fabsf(v[i].w))));
    }
#pragma unroll
    for (int off = 32; off > 0; off >>= 1)
        mx = fmaxf(mx, __shfl_xor(mx, off));

    __shared__ float wmax[4];
    const int wid = t >> 6;
    if ((t & 63) == 0) wmax[wid] = mx;
    __syncthreads();
    const float scale = fmaxf(fmaxf(fmaxf(wmax[0], wmax[1]),
                                    fmaxf(wmax[2], wmax[3])), 1e-5f);
    const float inv = 127.0f / scale;

    int* xqi = (int*)(xq + (size_t)m * IN_F);
#pragma unroll
    for (int i = 0; i < 4; ++i) {
        int q0 = (int)rintf(fminf(fmaxf(v[i].x * inv, -128.f), 127.f));
        int q1 = (int)rintf(fminf(fmaxf(v[i].y * inv, -128.f), 127.f));
        int q2 = (int)rintf(fminf(fmaxf(v[i].z * inv, -128.f), 127.f));
        int q3 = (int)rintf(fminf(fmaxf(v[i].w * inv, -128.f), 127.f));
        xqi[i * 256 + t] = (q0 & 255) | ((q1 & 255) << 8) |
                           ((q2 & 255) << 16) | (q3 << 24);
    }
    if (t == 0) xs[m] = scale;
}

// ---------------------------------------------------------------------------
// Kernel 2: ternary int32 weights -> int8 pack
// ---------------------------------------------------------------------------
__global__ __launch_bounds__(256) void k_wconv(const int* __restrict__ wt,
                                               int* __restrict__ w8) {
    const int total4 = OUT_F * IN_F / 4;
    int idx = blockIdx.x * 256 + threadIdx.x;
    const int stride = gridDim.x * 256;
    for (; idx < total4; idx += stride) {
        i32x4 w = *(const i32x4*)&wt[(size_t)idx * 4];
        w8[idx] = (w.x & 255) | ((w.y & 255) << 8) |
                  ((w.z & 255) << 16) | (w.w << 24);
    }
}

// ---------------------------------------------------------------------------
// Kernel 3: i8 GEMM — 8-phase, mfma_i32_16x16x64_i8 (R4's proven swizzle),
// 16 waves (1024 thr) per 256x256 block, wave-tile 64x64 -> acc = 64 VGPR,
// __launch_bounds__(1024,4) => 4 waves/SIMD (2x R4's TLP at same 128KB LDS).
//
// LDS: A[2buf][2half][128rows][128B] (buf*32768 + half*16384), B at +64KB.
// Swizzle: phys chunk = logical ^ (row&7); staging permutes global SOURCE
// within each row's 128B only (thread t: row t>>3, src chunk (t^(t>>3))&7).
// Fragment read: row = lane&15, chunk = (kk*4 + lane>>4) ^ (lane&7)
// -> 2-way per 16-lane group = free (R4-measured 0 conflicts).
//
// Schedule per iter (tile 2t in buf0, 2t+1 in buf1), 1 gload/thread/half:
//  ph1 rd aLo,bLo(buf0)  stage A1(2t+1)        MFMA(lo,lo)
//  ph2 rd bHi(buf0)      --                    MFMA(lo,hi)
//  ph3 rd aHi(buf0)      stage B0,B1(2t+2)     MFMA(hi,hi)   [B reads done ph2]
//  ph4 --                stage A0(2t+2)        MFMA(hi,lo)   [A reads done ph3]
//                        vmcnt(3)  -> retires tile 2t+1 exactly (read in ph5)
//  ph5-8 mirror on buf1; stages A1(2t+2), B0/B1(2t+3), A0(2t+3); vmcnt(3)
//  last iter: vmcnt(0).  In-flight steady state = 3 half-tiles.
// ---------------------------------------------------------------------------
__global__ __launch_bounds__(1024, 4) void k_gemm(
    const char*  __restrict__ Aq,     // [MTOK][IN_F] int8
    const char*  __restrict__ Bq,     // [OUT_F][IN_F] int8
    const float* __restrict__ xs,     // [MTOK]
    const float* __restrict__ wsp,    // [1]
    float*       __restrict__ C) {    // [MTOK][OUT_F]
    __shared__ __align__(16) char lds[131072];   // A: 0..64K, B: 64K..128K

    const int t    = threadIdx.x;
    const int lane = t & 63;
    const int wid  = t >> 6;          // 0..15
    const int wr   = wid >> 2;        // 0..3  (M quarter, 64 rows)
    const int wcn  = wid & 3;         // 0..3  (N quarter, 64 cols)

    // T1: XCD band mapping; grid 2048 = 32(M) x 64(N)
    const int bid = blockIdx.x;
    const int bn  = (bid & 7) * 8 + ((bid >> 3) & 7);
    const int bm  = bid >> 6;
    const int mBase = bm * BM;
    const int nBase = bn * BN;

    // --- staging source: thread t covers bytes [t*16, t*16+16) of a 16KB
    // half (row = t>>3, phys chunk = t&7 -> logical chunk (t^(t>>3))&7)
    const int r0 = t >> 3;                         // 0..127
    const int c0 = ((t ^ (t >> 3)) & 7) << 4;

#define STAGE_A(h, b, kt)                                                      \
    gload_lds16(Aq + (size_t)(mBase + (h) * 128 + r0) * IN_F + c0              \
                   + (size_t)(kt) * BKB,                                       \
                lds + (b) * 32768 + (h) * 16384 + wid * 1024)
#define STAGE_B(h, b, kt)                                                      \
    gload_lds16(Bq + (size_t)(nBase + (h) * 128 + r0) * IN_F + c0              \
                   + (size_t)(kt) * BKB,                                       \
                lds + 65536 + (b) * 32768 + (h) * 16384 + wid * 1024)

    // --- fragment read offsets: row = lane&15, chunk = (kk*4+(lane>>4))^(lane&7)
    int aOff[2];
#pragma unroll
    for (int kk = 0; kk < 2; ++kk)
        aOff[kk] = (lane & 15) * 128 + (((kk * 4 + (lane >> 4)) ^ (lane & 7)) << 4);
    const char* ldsA = lds + wr * 8192;            // + buf*32768 + mi*2048
    const char* ldsB = lds + 65536 + wcn * 8192;   // + buf*32768 + ni*2048

#define RD_A(dst, bOfs, miB)                                                   \
    _Pragma("unroll")                                                          \
    for (int mi = 0; mi < 2; ++mi)                                             \
        _Pragma("unroll")                                                      \
        for (int kk = 0; kk < 2; ++kk)                                         \
            dst[mi][kk] = *(const i32x4*)(ldsA + (bOfs) +                      \
                              ((miB) + mi) * 2048 + aOff[kk]);
#define RD_B(dst, bOfs, niB)                                                   \
    _Pragma("unroll")                                                          \
    for (int ni = 0; ni < 2; ++ni)                                             \
        _Pragma("unroll")                                                      \
        for (int kk = 0; kk < 2; ++kk)                                         \
            dst[ni][kk] = *(const i32x4*)(ldsB + (bOfs) +                      \
                              ((niB) + ni) * 2048 + aOff[kk]);
// kk OUTER: 4 independent acc chains per kk-slice (no back-to-back same-acc)
#define MFMA_Q(Af, MIB, Bf, NIB)                                               \
    __builtin_amdgcn_s_setprio(1);                                             \
    _Pragma("unroll")                                                          \
    for (int kk = 0; kk < 2; ++kk)                                             \
        _Pragma("unroll")                                                      \
        for (int mi = 0; mi < 2; ++mi)                                         \
            _Pragma("unroll")                                                  \
            for (int ni = 0; ni < 2; ++ni)                                     \
                acc[(MIB) + mi][(NIB) + ni] =                                  \
                    __builtin_amdgcn_mfma_i32_16x16x64_i8(                     \
                        Af[mi][kk], Bf[ni][kk], acc[(MIB) + mi][(NIB) + ni],   \
                        0, 0, 0);                                              \
    __builtin_amdgcn_s_setprio(0);
#define BAR()   __builtin_amdgcn_s_barrier()
#define LGKM0() asm volatile("s_waitcnt lgkmcnt(0)" ::: "memory")
#define VM3()   asm volatile("s_waitcnt vmcnt(3)" ::: "memory")
#define VM0()   asm volatile("s_waitcnt vmcnt(0)" ::: "memory")

    i32x4 acc[4][4];
#pragma unroll
    for (int i = 0; i < 4; ++i)
#pragma unroll
        for (int j = 0; j < 4; ++j)
            acc[i][j] = (i32x4){0, 0, 0, 0};

    i32x4 aLo[2][2], aHi[2][2], bLo[2][2], bHi[2][2];

    // ---- prologue: tile0 fully (4) + tile1 {B0,B1,A0} (3)
    STAGE_A(0, 0, 0); STAGE_A(1, 0, 0); STAGE_B(0, 0, 0); STAGE_B(1, 0, 0);
    STAGE_B(0, 1, 1); STAGE_B(1, 1, 1); STAGE_A(0, 1, 1);
    VM3();            // tile0 landed; tile1's 3 halves in flight
    BAR();

    for (int it = 0; it < NIT; ++it) {
        const int kt1 = 2 * it + 1;
        const int kn0 = 2 * it + 2;
        const int kn1 = 2 * it + 3;
        const bool more = (it < NIT - 1);

        // ---- ph1
        RD_A(aLo, 0, 0); RD_B(bLo, 0, 0);
        STAGE_A(1, 1, kt1);
        BAR(); LGKM0();
        MFMA_Q(aLo, 0, bLo, 0);
        BAR();
        // ---- ph2
        RD_B(bHi, 0, 2);
        BAR(); LGKM0();
        MFMA_Q(aLo, 0, bHi, 2);
        BAR();
        // ---- ph3  (buf0 B-reads ended at ph2 -> B stages safe)
        RD_A(aHi, 0, 2);
        if (more) { STAGE_B(0, 0, kn0); STAGE_B(1, 0, kn0); }
        BAR(); LGKM0();
        MFMA_Q(aHi, 2, bHi, 2);
        BAR();
        // ---- ph4  (buf0 A-reads ended at ph3 -> A stage safe)
        if (more) STAGE_A(0, 0, kn0);
        BAR();
        MFMA_Q(aHi, 2, bLo, 0);
        if (more) { VM3(); } else { VM0(); }
        BAR();
        // ---- ph5
        RD_A(aLo, 32768, 0); RD_B(bLo, 32768, 0);
        if (more) STAGE_A(1, 0, kn0);
        BAR(); LGKM0();
        MFMA_Q(aLo, 0, bLo, 0);
        BAR();
        // ---- ph6
        RD_B(bHi, 32768, 2);
        BAR(); LGKM0();
        MFMA_Q(aLo, 0, bHi, 2);
        BAR();
        // ---- ph7
        RD_A(aHi, 32768, 2);
        if (more) { STAGE_B(0, 1, kn1); STAGE_B(1, 1, kn1); }
        BAR(); LGKM0();
        MFMA_Q(aHi, 2, bHi, 2);
        BAR();
        // ---- ph8
        if (more) STAGE_A(0, 1, kn1);
        BAR();
        MFMA_Q(aHi, 2, bLo, 0);
        if (more) { VM3(); } else { VM0(); }
        BAR();
    }

    // ---- epilogue: D row = (lane>>4)*4 + r, col = lane&15 (verified R1-R4)
    const float wsc = wsp[0] * (1.0f / 127.0f);
#pragma unroll
    for (int mi = 0; mi < 4; ++mi) {
        float rs[4];
#pragma unroll
        for (int r = 0; r < 4; ++r)
            rs[r] = xs[mBase + wr * 64 + mi * 16 + (lane >> 4) * 4 + r] * wsc;
#pragma unroll
        for (int ni = 0; ni < 4; ++ni) {
            const int col = nBase + wcn * 64 + ni * 16 + (lane & 15);
#pragma unroll
            for (int r = 0; r < 4; ++r) {
                const int row = mBase + wr * 64 + mi * 16 + (lane >> 4) * 4 + r;
                C[(size_t)row * OUT_F + col] = (float)acc[mi][ni][r] * rs[r];
            }
        }
    }
}

// ---------------------------------------------------------------------------
extern "C" void kernel_launch(void* const* d_in, const int* in_sizes, int n_in,
                              void* d_out, int out_size, void* d_ws, size_t ws_size,
                              hipStream_t stream) {
    const float* x   = (const float*)d_in[0];
    const int*   wt  = (const int*)d_in[1];
    const float* wsp = (const float*)d_in[2];
    float* out = (float*)d_out;

    char*  w8 = (char*)d_ws;
    char*  xq = (char*)d_ws + (size_t)OUT_F * IN_F;
    float* xs = (float*)((char*)d_ws + (size_t)OUT_F * IN_F
                                     + (size_t)MTOK * IN_F);

    k_wconv<<<8192, 256, 0, stream>>>(wt, (int*)w8);
    k_quant<<<MTOK, 256, 0, stream>>>(x, xq, xs);

    const int grid = (MTOK / BM) * (OUT_F / BN);  // 32 * 64 = 2048
    k_gemm<<<grid, 1024, 0, stream>>>(xq, w8, xs, wsp, out);
}

// Round 7
// 587.420 us; speedup vs baseline: 1.1120x; 1.1120x over previous
//
#include <hip/hip_runtime.h>

#define IN_F 4096
#define OUT_F 16384
#define MTOK 8192   // B*S

#define BM 256
#define BN 256
#define BKB 128                 // K-bytes (=elements, i8) per K-tile
#define NKT (IN_F / BKB)        // 32 K-tiles
#define NIT (NKT / 2)           // 16 iterations, 2 K-tiles each

typedef __attribute__((ext_vector_type(4)))  int   i32x4;
typedef __attribute__((ext_vector_type(4)))  float f32x4;

__device__ __forceinline__ void gload_lds16(const void* g, void* l) {
    __builtin_amdgcn_global_load_lds(
        (const __attribute__((address_space(1))) void*)g,
        (__attribute__((address_space(3))) void*)l,
        16, 0, 0);
}

// ---------------------------------------------------------------------------
// Kernel 1: per-token absmax -> int8 quantize x, store scale
// ---------------------------------------------------------------------------
__global__ __launch_bounds__(256) void k_quant(const float* __restrict__ x,
                                               char* __restrict__ xq,
                                               float* __restrict__ xs) {
    const int m = blockIdx.x;
    const int t = threadIdx.x;
    const float* xrow = x + (size_t)m * IN_F;

    f32x4 v[4];
    float mx = 0.f;
#pragma unroll
    for (int i = 0; i < 4; ++i) {
        v[i] = *(const f32x4*)&xrow[(i * 256 + t) * 4];
        mx = fmaxf(mx, fmaxf(fmaxf(fabsf(v[i].x), fabsf(v[i].y)),
                             fmaxf(fabsf(v[i].z), fabsf(v[i].w))));
    }
#pragma unroll
    for (int off = 32; off > 0; off >>= 1)
        mx = fmaxf(mx, __shfl_xor(mx, off));

    __shared__ float wmax[4];
    const int wid = t >> 6;
    if ((t & 63) == 0) wmax[wid] = mx;
    __syncthreads();
    const float scale = fmaxf(fmaxf(fmaxf(wmax[0], wmax[1]),
                                    fmaxf(wmax[2], wmax[3])), 1e-5f);
    const float inv = 127.0f / scale;

    int* xqi = (int*)(xq + (size_t)m * IN_F);
#pragma unroll
    for (int i = 0; i < 4; ++i) {
        int q0 = (int)rintf(fminf(fmaxf(v[i].x * inv, -128.f), 127.f));
        int q1 = (int)rintf(fminf(fmaxf(v[i].y * inv, -128.f), 127.f));
        int q2 = (int)rintf(fminf(fmaxf(v[i].z * inv, -128.f), 127.f));
        int q3 = (int)rintf(fminf(fmaxf(v[i].w * inv, -128.f), 127.f));
        xqi[i * 256 + t] = (q0 & 255) | ((q1 & 255) << 8) |
                           ((q2 & 255) << 16) | (q3 << 24);
    }
    if (t == 0) xs[m] = scale;
}

// ---------------------------------------------------------------------------
// Kernel 2: ternary int32 weights -> int8 pack
// ---------------------------------------------------------------------------
__global__ __launch_bounds__(256) void k_wconv(const int* __restrict__ wt,
                                               int* __restrict__ w8) {
    const int total4 = OUT_F * IN_F / 4;
    int idx = blockIdx.x * 256 + threadIdx.x;
    const int stride = gridDim.x * 256;
    for (; idx < total4; idx += stride) {
        i32x4 w = *(const i32x4*)&wt[(size_t)idx * 4];
        w8[idx] = (w.x & 255) | ((w.y & 255) << 8) |
                  ((w.z & 255) << 16) | (w.w << 24);
    }
}

// ---------------------------------------------------------------------------
// Kernel 3: i8 GEMM — R4 structure (8-phase, 503 µs, 0 conflicts) with ONE
// change: kk is the OUTER loop of each MFMA cluster -> accumulator dep
// distance 8 (was 1). Everything else byte-identical to R4.
//
// 256x256 tile, BK=128 i8, 8 waves (2Mx4N), per-wave 128x64.
// LDS 128KB: A[2buf][2half][128rows][128B] + B same (+64KB offset).
// Swizzle: phys chunk = logical ^ (row&7); staging permutes global SOURCE
// within each row's 128B only. Fragment read: row=lane&15,
// chunk=(kk*4+(lane>>4))^(lane&7) -> measured 0 bank conflicts (R4).
// Schedule per iter (2 K-tiles: buf0=2t, buf1=2t+1), race-free stages:
//  ph1 rd A-lo+B-lo(buf0)  stage A1(2t+1)   MFMA q(lo,lo)
//  ph2 rd B-hi(buf0)       --               MFMA q(lo,hi)
//  ph3 rd A-hi(buf0)       stage B0(2t+2)   MFMA q(hi,hi)  [B reads done ph2]
//  ph4 --                  stage B1,A0      MFMA q(hi,lo)  vmcnt(6)
//  ph5-8 mirror on buf1; stages A1(2t+2), B0/B1/A0(2t+3);  vmcnt(6)
// vmcnt(6) retires exactly the next-needed K-tile (FIFO ledger, R5-derived);
// last iter vmcnt(0).
// ---------------------------------------------------------------------------
__global__ __launch_bounds__(512, 2) void k_gemm(
    const char*  __restrict__ Aq,     // [MTOK][IN_F] int8
    const char*  __restrict__ Bq,     // [OUT_F][IN_F] int8
    const float* __restrict__ xs,     // [MTOK]
    const float* __restrict__ wsp,    // [1]
    float*       __restrict__ C) {    // [MTOK][OUT_F]
    __shared__ __align__(16) char lds[131072];   // A: 0..64K, B: 64K..128K

    const int t    = threadIdx.x;
    const int lane = t & 63;
    const int wid  = t >> 6;
    const int wr   = wid >> 2;        // 0..1  (M half)
    const int wc   = wid & 3;         // 0..3  (N quarter)

    // L2/L3-band grid mapping: XCD (bid&7) owns a bn band of 8.
    const int bid = blockIdx.x;
    const int bn  = (bid & 7) * 8 + ((bid >> 3) & 7);
    const int bm  = bid >> 6;
    const int mBase = bm * BM;
    const int nBase = bn * BN;

    // --- staging source: phys chunk pc = j*512+t; row = pc>>3,
    // src col-chunk = ((pc&7) ^ (row&7)) * 16
    const int r0 = t >> 3;
    const int c0 = ((t ^ r0) & 7) * 16;

#define STAGE_A(h, b, kt) do {                                                 \
        const size_t _s = (size_t)(mBase + (h) * 128 + r0) * IN_F + c0         \
                        + (size_t)(kt) * BKB;                                  \
        char* _d = lds + (b) * 32768 + (h) * 16384 + wid * 1024;               \
        gload_lds16(Aq + _s, _d);                                              \
        gload_lds16(Aq + _s + (size_t)64 * IN_F, _d + 8192);                   \
    } while (0)
#define STAGE_B(h, b, kt) do {                                                 \
        const size_t _s = (size_t)(nBase + (h) * 128 + r0) * IN_F + c0         \
                        + (size_t)(kt) * BKB;                                  \
        char* _d = lds + 65536 + (b) * 32768 + (h) * 16384 + wid * 1024;       \
        gload_lds16(Bq + _s, _d);                                              \
        gload_lds16(Bq + _s + (size_t)64 * IN_F, _d + 8192);                   \
    } while (0)

    // --- fragment read offsets: row = lane&15, chunk = (kk*4+(lane>>4))^(lane&7)
    int fOff[2];
#pragma unroll
    for (int kk = 0; kk < 2; ++kk)
        fOff[kk] = (lane & 15) * 128 + (((kk * 4 + (lane >> 4)) ^ (lane & 7)) << 4);
    const char* ldsA = lds + wr * 16384;                    // + buf*32768 + mi*2048
    const char* ldsB = lds + 65536 + (wc >> 1) * 16384;     // + buf*32768 + ni*2048
    const int bNi = (wc & 1) * 4;   // wave's ni sub-offset within its B half

#define RD_A(dst, bOfs, miB)                                                   \
    _Pragma("unroll")                                                          \
    for (int mi = 0; mi < 4; ++mi)                                             \
        _Pragma("unroll")                                                      \
        for (int kk = 0; kk < 2; ++kk)                                         \
            dst[mi][kk] = *(const i32x4*)(ldsA + (bOfs) +                      \
                              ((miB) + mi) * 2048 + fOff[kk]);
#define RD_B(dst, bOfs, niB)                                                   \
    _Pragma("unroll")                                                          \
    for (int ni = 0; ni < 2; ++ni)                                             \
        _Pragma("unroll")                                                      \
        for (int kk = 0; kk < 2; ++kk)                                         \
            dst[ni][kk] = *(const i32x4*)(ldsB + (bOfs) +                      \
                              (bNi + (niB) + ni) * 2048 + fOff[kk]);
// kk OUTER: 8 independent acc targets between reuses (dep distance 8)
#define MFMA_Q(Af, MIB, Bf, NIB)                                               \
    __builtin_amdgcn_s_setprio(1);                                             \
    _Pragma("unroll")                                                          \
    for (int kk = 0; kk < 2; ++kk)                                             \
        _Pragma("unroll")                                                      \
        for (int mi = 0; mi < 4; ++mi)                                         \
            _Pragma("unroll")                                                  \
            for (int ni = 0; ni < 2; ++ni)                                     \
                acc[(MIB) + mi][(NIB) + ni] =                                  \
                    __builtin_amdgcn_mfma_i32_16x16x64_i8(                     \
                        Af[mi][kk], Bf[ni][kk], acc[(MIB) + mi][(NIB) + ni],   \
                        0, 0, 0);                                              \
    __builtin_amdgcn_s_setprio(0);
#define BAR()   __builtin_amdgcn_s_barrier()
#define LGKM0() asm volatile("s_waitcnt lgkmcnt(0)" ::: "memory")
#define VM6()   asm volatile("s_waitcnt vmcnt(6)" ::: "memory")
#define VM0()   asm volatile("s_waitcnt vmcnt(0)" ::: "memory")

    i32x4 acc[8][4];
#pragma unroll
    for (int i = 0; i < 8; ++i)
#pragma unroll
        for (int j = 0; j < 4; ++j)
            acc[i][j] = (i32x4){0, 0, 0, 0};

    i32x4 aLo[4][2], aHi[4][2], bLo[2][2], bHi[2][2];

    // ---- prologue: tile0 fully (8 loads) + tile1 {B0,B1,A0} (6 loads)
    STAGE_A(0, 0, 0); STAGE_A(1, 0, 0); STAGE_B(0, 0, 0); STAGE_B(1, 0, 0);
    STAGE_B(0, 1, 1); STAGE_B(1, 1, 1); STAGE_A(0, 1, 1);
    VM6();           // tile0's 8 retired; tile1's 3 halves (6 loads) in flight
    BAR();

    for (int it = 0; it < NIT; ++it) {
        const int kt1 = 2 * it + 1;
        const int kn0 = 2 * it + 2;
        const int kn1 = 2 * it + 3;
        const bool more = (it < NIT - 1);

        // ---- ph1
        RD_A(aLo, 0, 0); RD_B(bLo, 0, 0);
        STAGE_A(1, 1, kt1);
        BAR(); LGKM0();
        MFMA_Q(aLo, 0, bLo, 0);
        BAR();
        // ---- ph2
        RD_B(bHi, 0, 2);
        BAR(); LGKM0();
        MFMA_Q(aLo, 0, bHi, 2);
        BAR();
        // ---- ph3  (buf0 B-reads ended at ph2 -> B stages safe)
        RD_A(aHi, 0, 4);
        if (more) STAGE_B(0, 0, kn0);
        BAR(); LGKM0();
        MFMA_Q(aHi, 4, bHi, 2);
        BAR();
        // ---- ph4  (buf0 A-reads ended at ph3 -> A stage safe)
        if (more) { STAGE_B(1, 0, kn0); STAGE_A(0, 0, kn0); }
        BAR();
        MFMA_Q(aHi, 4, bLo, 0);
        if (more) { VM6(); } else { VM0(); }
        BAR();
        // ---- ph5
        RD_A(aLo, 32768, 0); RD_B(bLo, 32768, 0);
        if (more) STAGE_A(1, 0, kn0);
        BAR(); LGKM0();
        MFMA_Q(aLo, 0, bLo, 0);
        BAR();
        // ---- ph6
        RD_B(bHi, 32768, 2);
        BAR(); LGKM0();
        MFMA_Q(aLo, 0, bHi, 2);
        BAR();
        // ---- ph7
        RD_A(aHi, 32768, 4);
        if (more) STAGE_B(0, 1, kn1);
        BAR(); LGKM0();
        MFMA_Q(aHi, 4, bHi, 2);
        BAR();
        // ---- ph8
        if (more) { STAGE_B(1, 1, kn1); STAGE_A(0, 1, kn1); }
        BAR();
        MFMA_Q(aHi, 4, bLo, 0);
        if (more) { VM6(); } else { VM0(); }
        BAR();
    }

    // ---- epilogue: D row = (lane>>4)*4 + r, col = lane&15 (verified R1-R4)
    const float wsc = wsp[0] * (1.0f / 127.0f);
#pragma unroll
    for (int mi = 0; mi < 8; ++mi) {
        float rs[4];
#pragma unroll
        for (int r = 0; r < 4; ++r)
            rs[r] = xs[mBase + wr * 128 + mi * 16 + (lane >> 4) * 4 + r] * wsc;
#pragma unroll
        for (int ni = 0; ni < 4; ++ni) {
            const int col = nBase + wc * 64 + ni * 16 + (lane & 15);
#pragma unroll
            for (int r = 0; r < 4; ++r) {
                const int row = mBase + wr * 128 + mi * 16 + (lane >> 4) * 4 + r;
                C[(size_t)row * OUT_F + col] = (float)acc[mi][ni][r] * rs[r];
            }
        }
    }
}

// ---------------------------------------------------------------------------
extern "C" void kernel_launch(void* const* d_in, const int* in_sizes, int n_in,
                              void* d_out, int out_size, void* d_ws, size_t ws_size,
                              hipStream_t stream) {
    const float* x   = (const float*)d_in[0];
    const int*   wt  = (const int*)d_in[1];
    const float* wsp = (const float*)d_in[2];
    float* out = (float*)d_out;

    char*  w8 = (char*)d_ws;
    char*  xq = (char*)d_ws + (size_t)OUT_F * IN_F;
    float* xs = (float*)((char*)d_ws + (size_t)OUT_F * IN_F
                                     + (size_t)MTOK * IN_F);

    k_wconv<<<8192, 256, 0, stream>>>(wt, (int*)w8);
    k_quant<<<MTOK, 256, 0, stream>>>(x, xq, xs);

    const int grid = (MTOK / BM) * (OUT_F / BN);  // 32 * 64 = 2048
    k_gemm<<<grid, 512, 0, stream>>>(xq, w8, xs, wsp, out);
}